// Round 1
// baseline (2034.778 us; speedup 1.0000x reference)
//
#include <hip/hip_runtime.h>
#include <hip/hip_bf16.h>
#include <cmath>

#define HD 96          // H * D = 3 * 32
#define NHEAD 3
#define DOUT 32
#define SLOPE 0.01f
#define BN_EPS 1e-5f

static constexpr int NUc = 100000;
static constexpr int NIc = 100000;
static constexpr int Ec  = 500000;

// ---------------- atomics helpers ----------------
__device__ inline void atomAddF(float* p, float v) {
    unsafeAtomicAdd(p, v);   // HW global_atomic_add_f32 on gfx9xx
}

__device__ inline void atomicMaxF(float* addr, float v) {
    // sign-split trick; init must be -inf (0xff800000).
    // NOTE: softmax max is only for numerical stability (cancels exactly),
    // so rare -0.0 edge cases are mathematically harmless.
    if (v >= 0.f) atomicMax((int*)addr, __float_as_int(v));
    else          atomicMin((unsigned int*)addr, __float_as_uint(v));
}

// ---------------- dense transform: out = X @ W (+bias), el/er = head-dot with attn ----------------
// One block = 128 nodes, W staged in LDS, X row held in registers.
template<int DIN, bool HASF, bool HASE, bool HASB>
__global__ __launch_bounds__(128)
void transform_k(const float* __restrict__ X, const float* __restrict__ W,
                 const float* __restrict__ attn, const float* __restrict__ bias,
                 float* __restrict__ outF, float* __restrict__ outE, int N)
{
    __shared__ float Ws[DIN * HD];
    __shared__ float As[HD];
    __shared__ float Bs[HD];
    __shared__ float Xs[128 * (DIN + 1)];   // +1 pad: kills bank conflicts on row reads

    const int t = threadIdx.x;
    for (int i = t; i < DIN * HD; i += 128) Ws[i] = W[i];
    if (t < HD) {
        As[t] = HASE ? attn[t] : 0.f;
        Bs[t] = HASB ? bias[t] : 0.f;
    }
    const int base = blockIdx.x * 128;
    const int nv = min(128, N - base);
    constexpr int SH = (DIN == 64) ? 6 : 5;
    for (int i = t; i < nv * DIN; i += 128) {
        const int r = i >> SH, c = i & (DIN - 1);
        Xs[r * (DIN + 1) + c] = X[(size_t)base * DIN + i];   // coalesced
    }
    __syncthreads();
    if (t >= nv) return;

    float xr[DIN];
    #pragma unroll
    for (int k = 0; k < DIN; ++k) xr[k] = Xs[t * (DIN + 1) + k];

    const size_t n = (size_t)(base + t);
    for (int h = 0; h < NHEAD; ++h) {
        float eh = 0.f;
        for (int j = h * 32; j < (h + 1) * 32; j += 4) {
            float a0 = 0.f, a1 = 0.f, a2 = 0.f, a3 = 0.f;
            #pragma unroll
            for (int k = 0; k < DIN; ++k) {
                const float4 w = *reinterpret_cast<const float4*>(&Ws[k * HD + j]);
                const float x = xr[k];
                a0 = fmaf(x, w.x, a0); a1 = fmaf(x, w.y, a1);
                a2 = fmaf(x, w.z, a2); a3 = fmaf(x, w.w, a3);
            }
            if (HASB) { a0 += Bs[j]; a1 += Bs[j+1]; a2 += Bs[j+2]; a3 += Bs[j+3]; }
            if (HASF) {
                float4 o; o.x = a0; o.y = a1; o.z = a2; o.w = a3;
                *reinterpret_cast<float4*>(&outF[n * HD + j]) = o;
            }
            if (HASE) eh += a0*As[j] + a1*As[j+1] + a2*As[j+2] + a3*As[j+3];
        }
        if (HASE) outE[n * NHEAD + h] = eh;
    }
}

// ---------------- edge phase ----------------
__global__ __launch_bounds__(256)
void fill_md_k(float* __restrict__ m, float* __restrict__ den, int n) {
    const int i = blockIdx.x * 256 + threadIdx.x;
    if (i < n) { m[i] = -INFINITY; den[i] = 0.f; }
}

__global__ __launch_bounds__(256)
void edge_max_k(const int* __restrict__ src, const int* __restrict__ dst,
                const float* __restrict__ el, const float* __restrict__ er,
                float* __restrict__ m)
{
    const int e = blockIdx.x * 256 + threadIdx.x;
    if (e >= Ec) return;
    const int s = src[e], d = dst[e];
    #pragma unroll
    for (int h = 0; h < NHEAD; ++h) {
        float v = el[s * NHEAD + h] + er[d * NHEAD + h];
        v = v > 0.f ? v : SLOPE * v;
        atomicMaxF(&m[d * NHEAD + h], v);
    }
}

__global__ __launch_bounds__(256)
void edge_expsum_k(const int* __restrict__ src, const int* __restrict__ dst,
                   const float* __restrict__ el, const float* __restrict__ er,
                   const float* __restrict__ m, float* __restrict__ exb,
                   float* __restrict__ den)
{
    const int e = blockIdx.x * 256 + threadIdx.x;
    if (e >= Ec) return;
    const int s = src[e], d = dst[e];
    #pragma unroll
    for (int h = 0; h < NHEAD; ++h) {
        float v = el[s * NHEAD + h] + er[d * NHEAD + h];
        v = v > 0.f ? v : SLOPE * v;
        const float ex = expf(v - m[d * NHEAD + h]);
        exb[e * NHEAD + h] = ex;
        atomAddF(&den[d * NHEAD + h], ex);
    }
}

__global__ __launch_bounds__(256)
void edge_msg_k(const int* __restrict__ src, const int* __restrict__ dst,
                const float* __restrict__ exb, const float* __restrict__ den,
                const float* __restrict__ fs, float* __restrict__ acc)
{
    const int i = blockIdx.x * 256 + threadIdx.x;   // over E*HD = 48M < 2^31
    if (i >= Ec * HD) return;
    const int e = i / HD;
    const int j = i - e * HD;
    const int s = src[e], d = dst[e];
    const int h = j >> 5;
    const float a = exb[e * NHEAD + h] / den[d * NHEAD + h];
    atomAddF(&acc[(size_t)d * HD + j], fs[(size_t)s * HD + j] * a);
}

// ---------------- linear + BN(eval) + ReLU ----------------
__global__ __launch_bounds__(256)
void lin_bn_relu_k(const float* __restrict__ X, const float* __restrict__ Wl,
                   const float* __restrict__ bl, const float* __restrict__ bn,
                   float* __restrict__ out, int N)
{
    __shared__ float Ws[HD * DOUT];
    const int t = threadIdx.x;
    for (int i = t; i < HD * DOUT; i += 256) Ws[i] = Wl[i];
    __syncthreads();
    const int o = t & 31, ln = t >> 5;
    const int n = blockIdx.x * 8 + ln;
    if (n >= N) return;
    float acc = bl[o];
    const float* xrow = X + (size_t)n * HD;
    #pragma unroll
    for (int k4 = 0; k4 < HD; k4 += 4) {
        const float4 xv = *reinterpret_cast<const float4*>(xrow + k4);
        acc = fmaf(xv.x, Ws[(k4    ) * DOUT + o], acc);
        acc = fmaf(xv.y, Ws[(k4 + 1) * DOUT + o], acc);
        acc = fmaf(xv.z, Ws[(k4 + 2) * DOUT + o], acc);
        acc = fmaf(xv.w, Ws[(k4 + 3) * DOUT + o], acc);
    }
    const float gamma = bn[o], beta = bn[DOUT + o], mean = bn[2 * DOUT + o], var = bn[3 * DOUT + o];
    const float y = (acc - mean) * gamma * rsqrtf(var + BN_EPS) + beta;
    out[(size_t)n * DOUT + o] = fmaxf(y, 0.f);
}

// ---------------- host ----------------
extern "C" void kernel_launch(void* const* d_in, const int* in_sizes, int n_in,
                              void* d_out, int out_size, void* d_ws, size_t ws_size,
                              hipStream_t stream)
{
    const float* emb_user = (const float*)d_in[0];
    const float* emb_item = (const float*)d_in[1];
    const float* W1    = (const float*)d_in[2];
    const float* attn1 = (const float*)d_in[3];
    const float* res1  = (const float*)d_in[4];
    const float* bias1 = (const float*)d_in[5];
    const float* nnW1  = (const float*)d_in[6];
    const float* nnb1  = (const float*)d_in[7];
    const float* bn1   = (const float*)d_in[8];
    const float* W2    = (const float*)d_in[9];
    const float* attn2 = (const float*)d_in[10];
    const float* res2  = (const float*)d_in[11];
    const float* bias2 = (const float*)d_in[12];
    const float* nnW2  = (const float*)d_in[13];
    const float* nnb2  = (const float*)d_in[14];
    const float* bn2   = (const float*)d_in[15];
    const int* go_src   = (const int*)d_in[16];
    const int* go_dst   = (const int*)d_in[17];
    const int* back_src = (const int*)d_in[18];
    const int* back_dst = (const int*)d_in[19];

    float* ws = (float*)d_ws;
    size_t off = 0;
    float* fs  = ws + off; off += (size_t)100000 * HD;     // 9.6M
    float* acc = ws + off; off += (size_t)100000 * HD;     // 9.6M
    float* el  = ws + off; off += 300000;
    float* er  = ws + off; off += 300000;
    float* mm  = ws + off; off += 300000;
    float* den = ws + off; off += 300000;
    float* exb = ws + off; off += (size_t)Ec * NHEAD;      // 1.5M
    float* hu1 = ws + off; off += (size_t)100000 * DOUT;   // 3.2M
    float* hi1 = ws + off; off += (size_t)100000 * DOUT;   // 3.2M
    // total ~28.3M floats = 113 MB

    float* out_user = (float*)d_out;
    float* out_item = out_user + (size_t)NUc * DOUT;

    auto run_rel = [&](const float* srcX, const float* dstX, int Din,
                       const float* W, const float* aL, const float* aR,
                       const float* rW, const float* bs,
                       const int* es, const int* ed,
                       const float* lW, const float* lb, const float* bnp,
                       float* outp, int Nsrc, int Ndst)
    {
        const dim3 tb(128);
        if (Din == 64) {
            transform_k<64, true,  true,  false><<<(Nsrc + 127) / 128, tb, 0, stream>>>(srcX, W,  aL, nullptr, fs,      el, Nsrc);
            transform_k<64, false, true,  false><<<(Ndst + 127) / 128, tb, 0, stream>>>(dstX, W,  aR, nullptr, nullptr, er, Ndst);
            transform_k<64, true,  false, true ><<<(Ndst + 127) / 128, tb, 0, stream>>>(dstX, rW, nullptr, bs, acc, nullptr, Ndst);
        } else {
            transform_k<32, true,  true,  false><<<(Nsrc + 127) / 128, tb, 0, stream>>>(srcX, W,  aL, nullptr, fs,      el, Nsrc);
            transform_k<32, false, true,  false><<<(Ndst + 127) / 128, tb, 0, stream>>>(dstX, W,  aR, nullptr, nullptr, er, Ndst);
            transform_k<32, true,  false, true ><<<(Ndst + 127) / 128, tb, 0, stream>>>(dstX, rW, nullptr, bs, acc, nullptr, Ndst);
        }
        fill_md_k<<<(Ndst * NHEAD + 255) / 256, 256, 0, stream>>>(mm, den, Ndst * NHEAD);
        edge_max_k<<<(Ec + 255) / 256, 256, 0, stream>>>(es, ed, el, er, mm);
        edge_expsum_k<<<(Ec + 255) / 256, 256, 0, stream>>>(es, ed, el, er, mm, exb, den);
        edge_msg_k<<<(Ec * HD + 255) / 256, 256, 0, stream>>>(es, ed, exb, den, fs, acc);
        lin_bn_relu_k<<<(Ndst + 7) / 8, 256, 0, stream>>>(acc, lW, lb, bnp, outp, Ndst);
    };

    // ---- layer 1 ----
    // 'go': src=user, dst=item. W1[0], attn1[0,0]/[0,1], res1[0], bias1[0]; item MLP = nnW1[1]/nnb1[1]/bn1[1]
    run_rel(emb_user, emb_item, 64,
            W1 + 0, attn1 + 0, attn1 + 96, res1 + 0, bias1 + 0,
            go_src, go_dst,
            nnW1 + HD * DOUT, nnb1 + DOUT, bn1 + 4 * DOUT,
            hi1, NUc, NIc);
    // 'back': src=item, dst=user. W1[1], attn1[1,0]/[1,1], res1[1], bias1[1]; user MLP = nnW1[0]/nnb1[0]/bn1[0]
    run_rel(emb_item, emb_user, 64,
            W1 + 64 * HD, attn1 + 192, attn1 + 288, res1 + 64 * HD, bias1 + HD,
            back_src, back_dst,
            nnW1 + 0, nnb1 + 0, bn1 + 0,
            hu1, NIc, NUc);

    // ---- layer 2 ----
    run_rel(hu1, hi1, 32,
            W2 + 0, attn2 + 0, attn2 + 96, res2 + 0, bias2 + 0,
            go_src, go_dst,
            nnW2 + HD * DOUT, nnb2 + DOUT, bn2 + 4 * DOUT,
            out_item, NUc, NIc);
    run_rel(hi1, hu1, 32,
            W2 + 32 * HD, attn2 + 192, attn2 + 288, res2 + 32 * HD, bias2 + HD,
            back_src, back_dst,
            nnW2 + 0, nnb2 + 0, bn2 + 0,
            out_user, NIc, NUc);
}

// Round 3
// 1437.138 us; speedup vs baseline: 1.4159x; 1.4159x over previous
//
#include <hip/hip_runtime.h>
#include <cmath>

#define NHEAD 3
#define HD 96          // H * D = 3 * 32
#define DOUT 32
#define SLOPE 0.01f
#define BN_EPS 1e-5f

static constexpr int NN = 100000;   // NU == NI == 100000
static constexpr int Ec = 500000;

// ---------------- job structs ----------------
struct TJob { const float* X; const float* W; const float* Wsm; const float* bias; float* outF; float* outE; };
struct AWJob { const float* W; const float* a; float* out; int din; };
struct AWJobs { AWJob j[8]; };

// ---------------- attn-weight pre-reduction: Wl/Wr[k,h] = sum_d W[k, h*32+d] * a[h*32+d] ----------------
__global__ __launch_bounds__(192)
void attw_k(AWJobs js) {
    AWJob jb = js.j[blockIdx.x];
    const int t = threadIdx.x;
    const int k = t / 3, h = t - 3 * (t / 3);
    if (k < jb.din) {
        const float* wrow = jb.W + (size_t)k * HD + h * 32;
        const float* av = jb.a + h * 32;
        float s = 0.f;
        #pragma unroll
        for (int d = 0; d < 32; ++d) s = fmaf(wrow[d], av[d], s);
        jb.out[k * 3 + h] = s;
    }
}

// ---------------- CSR build ----------------
__global__ void zero_k(int* p, int n) {
    const int i = blockIdx.x * 256 + threadIdx.x;
    if (i < n) p[i] = 0;
}

__global__ void hist_k(const int* __restrict__ gd, const int* __restrict__ bd, int* __restrict__ cnt) {
    const int i = blockIdx.x * 256 + threadIdx.x;
    if (i < Ec) atomicAdd(&cnt[gd[i]], 1);
    else if (i < 2 * Ec) atomicAdd(&cnt[NN + bd[i - Ec]], 1);
}

__global__ __launch_bounds__(1024)
void scan_k(int* cnt, int* off) {
    const int rel = blockIdx.x;
    cnt += rel * NN; off += rel * (NN + 1);
    __shared__ int ps[1024];
    const int t = threadIdx.x;
    const int chunk = (NN + 1023) / 1024;
    const int beg = t * chunk, end = min(beg + chunk, NN);
    int s = 0;
    for (int i = beg; i < end; ++i) s += cnt[i];
    ps[t] = s;
    __syncthreads();
    for (int d = 1; d < 1024; d <<= 1) {
        const int v = (t >= d) ? ps[t - d] : 0;
        __syncthreads();
        ps[t] += v;
        __syncthreads();
    }
    int run = (t == 0) ? 0 : ps[t - 1];
    for (int i = beg; i < end; ++i) { const int c = cnt[i]; off[i] = run; run += c; cnt[i] = 0; }
    if (t == 1023) off[NN] = run;
}

__global__ void fill_k(const int* __restrict__ gs, const int* __restrict__ gd,
                       const int* __restrict__ bs, const int* __restrict__ bd,
                       const int* __restrict__ off, int* __restrict__ cur, int* __restrict__ csr) {
    const int i = blockIdx.x * 256 + threadIdx.x;
    if (i < Ec) {
        const int d = gd[i];
        const int p = off[d] + atomicAdd(&cur[d], 1);
        csr[p] = gs[i];
    } else if (i < 2 * Ec) {
        const int d = bd[i - Ec];
        const int p = off[(NN + 1) + d] + atomicAdd(&cur[NN + d], 1);
        csr[Ec + p] = bs[i - Ec];
    }
}

// ---------------- dense transform: outF = X@W (+bias), outE = X@Wsm (3 attn dots) ----------------
template<int DIN>
__global__ __launch_bounds__(128)
void transform_k(TJob jA, TJob jB, int N) {
    const TJob j = (blockIdx.y == 0) ? jA : jB;
    __shared__ float Ws[DIN * HD];
    __shared__ float Wsm[DIN * 3];
    __shared__ float Bs[HD];
    __shared__ float Xs[128 * (DIN + 1)];
    const int t = threadIdx.x;
    for (int i = t; i < DIN * HD; i += 128) Ws[i] = j.W[i];
    for (int i = t; i < DIN * 3; i += 128) Wsm[i] = j.Wsm[i];
    if (t < HD) Bs[t] = j.bias ? j.bias[t] : 0.f;
    const int base = blockIdx.x * 128;
    const int nv = min(128, N - base);
    for (int i = t; i < nv * DIN; i += 128) {
        const int r = i / DIN, c = i - r * DIN;
        Xs[r * (DIN + 1) + c] = j.X[(size_t)base * DIN + i];   // coalesced
    }
    __syncthreads();
    if (t >= nv) return;

    float xr[DIN];
    #pragma unroll
    for (int k = 0; k < DIN; ++k) xr[k] = Xs[t * (DIN + 1) + k];
    const size_t n = (size_t)(base + t);

    float e0 = 0.f, e1 = 0.f, e2 = 0.f;
    #pragma unroll
    for (int k = 0; k < DIN; ++k) {
        e0 = fmaf(xr[k], Wsm[k * 3 + 0], e0);
        e1 = fmaf(xr[k], Wsm[k * 3 + 1], e1);
        e2 = fmaf(xr[k], Wsm[k * 3 + 2], e2);
    }
    j.outE[n * 3 + 0] = e0; j.outE[n * 3 + 1] = e1; j.outE[n * 3 + 2] = e2;

    for (int jo = 0; jo < HD; jo += 4) {
        float a0 = Bs[jo], a1 = Bs[jo + 1], a2 = Bs[jo + 2], a3 = Bs[jo + 3];
        #pragma unroll
        for (int k = 0; k < DIN; ++k) {
            const float4 w = *reinterpret_cast<const float4*>(&Ws[k * HD + jo]);
            const float x = xr[k];
            a0 = fmaf(x, w.x, a0); a1 = fmaf(x, w.y, a1);
            a2 = fmaf(x, w.z, a2); a3 = fmaf(x, w.w, a3);
        }
        float4 o; o.x = a0; o.y = a1; o.z = a2; o.w = a3;
        *reinterpret_cast<float4*>(&j.outF[n * HD + jo]) = o;
    }
}

// ---------------- fused softmax + aggregation: one wave per dst node ----------------
__global__ __launch_bounds__(256)
void agg_k(const int* __restrict__ off, const int* __restrict__ srcs,
           const float* __restrict__ el, const float* __restrict__ er,
           const float* __restrict__ fs, float* __restrict__ acc, int N)
{
    const int node = (int)((blockIdx.x * 256u + threadIdx.x) >> 6);
    const int lane = threadIdx.x & 63;
    if (node >= N) return;
    const int o0 = off[node], o1 = off[node + 1];
    const float er0 = er[node * 3 + 0], er1 = er[node * 3 + 1], er2 = er[node * 3 + 2];

    // phase 1: edge-parallel max per head
    float m0 = -INFINITY, m1 = -INFINITY, m2 = -INFINITY;
    for (int p = o0 + lane; p < o1; p += 64) {
        const int s = srcs[p];
        float v0 = el[s * 3 + 0] + er0; v0 = v0 > 0.f ? v0 : SLOPE * v0;
        float v1 = el[s * 3 + 1] + er1; v1 = v1 > 0.f ? v1 : SLOPE * v1;
        float v2 = el[s * 3 + 2] + er2; v2 = v2 > 0.f ? v2 : SLOPE * v2;
        m0 = fmaxf(m0, v0); m1 = fmaxf(m1, v1); m2 = fmaxf(m2, v2);
    }
    #pragma unroll
    for (int d = 32; d; d >>= 1) {
        m0 = fmaxf(m0, __shfl_xor(m0, d));
        m1 = fmaxf(m1, __shfl_xor(m1, d));
        m2 = fmaxf(m2, __shfl_xor(m2, d));
    }
    // phase 2: edge-parallel exp-sum per head
    float s0 = 0.f, s1 = 0.f, s2 = 0.f;
    for (int p = o0 + lane; p < o1; p += 64) {
        const int s = srcs[p];
        float v0 = el[s * 3 + 0] + er0; v0 = v0 > 0.f ? v0 : SLOPE * v0;
        float v1 = el[s * 3 + 1] + er1; v1 = v1 > 0.f ? v1 : SLOPE * v1;
        float v2 = el[s * 3 + 2] + er2; v2 = v2 > 0.f ? v2 : SLOPE * v2;
        s0 += __expf(v0 - m0); s1 += __expf(v1 - m1); s2 += __expf(v2 - m2);
    }
    #pragma unroll
    for (int d = 32; d; d >>= 1) {
        s0 += __shfl_xor(s0, d); s1 += __shfl_xor(s1, d); s2 += __shfl_xor(s2, d);
    }
    const float r0 = s0 > 0.f ? 1.f / s0 : 0.f;
    const float r1 = s1 > 0.f ? 1.f / s1 : 0.f;
    const float r2 = s2 > 0.f ? 1.f / s2 : 0.f;

    // phase 3: serial-edge, channel-parallel accumulate
    const int h = lane >> 5;                      // head for ch = lane (0..63)
    const float erh = h ? er1 : er0;
    const float mh  = h ? m1  : m0;
    const float rh  = h ? r1  : r0;
    float a0 = 0.f, a1 = 0.f;
    for (int p = o0; p < o1; ++p) {
        const int s = srcs[p];
        float v = el[s * 3 + h] + erh; v = v > 0.f ? v : SLOPE * v;
        const float w = __expf(v - mh) * rh;
        float v2 = el[s * 3 + 2] + er2; v2 = v2 > 0.f ? v2 : SLOPE * v2;
        const float w2 = __expf(v2 - m2) * r2;
        const size_t fb = (size_t)s * HD;
        a0 = fmaf(fs[fb + lane], w, a0);
        if (lane < 32) a1 = fmaf(fs[fb + 64 + lane], w2, a1);
    }
    const size_t ab = (size_t)node * HD;
    acc[ab + lane] += a0;                          // acc holds res + bias
    if (lane < 32) acc[ab + 64 + lane] += a1;
}

// ---------------- linear + BN(eval) + ReLU ----------------
__global__ __launch_bounds__(256)
void lin_bn_relu_k(const float* __restrict__ X, const float* __restrict__ Wl,
                   const float* __restrict__ bl, const float* __restrict__ bn,
                   float* __restrict__ out, int N)
{
    __shared__ float Ws[HD * DOUT];
    const int t = threadIdx.x;
    for (int i = t; i < HD * DOUT; i += 256) Ws[i] = Wl[i];
    __syncthreads();
    const int o = t & 31, ln = t >> 5;
    const int n = blockIdx.x * 8 + ln;
    if (n >= N) return;
    float acc = bl[o];
    const float* xrow = X + (size_t)n * HD;
    #pragma unroll
    for (int k4 = 0; k4 < HD; k4 += 4) {
        const float4 xv = *reinterpret_cast<const float4*>(xrow + k4);
        acc = fmaf(xv.x, Ws[(k4    ) * DOUT + o], acc);
        acc = fmaf(xv.y, Ws[(k4 + 1) * DOUT + o], acc);
        acc = fmaf(xv.z, Ws[(k4 + 2) * DOUT + o], acc);
        acc = fmaf(xv.w, Ws[(k4 + 3) * DOUT + o], acc);
    }
    const float gamma = bn[o], beta = bn[DOUT + o], mean = bn[2 * DOUT + o], var = bn[3 * DOUT + o];
    const float y = (acc - mean) * gamma * rsqrtf(var + BN_EPS) + beta;
    out[(size_t)n * DOUT + o] = fmaxf(y, 0.f);
}

// ---------------- host ----------------
extern "C" void kernel_launch(void* const* d_in, const int* in_sizes, int n_in,
                              void* d_out, int out_size, void* d_ws, size_t ws_size,
                              hipStream_t stream)
{
    const float* emb_user = (const float*)d_in[0];
    const float* emb_item = (const float*)d_in[1];
    const float* W1    = (const float*)d_in[2];
    const float* attn1 = (const float*)d_in[3];
    const float* res1  = (const float*)d_in[4];
    const float* bias1 = (const float*)d_in[5];
    const float* nnW1  = (const float*)d_in[6];
    const float* nnb1  = (const float*)d_in[7];
    const float* bn1   = (const float*)d_in[8];
    const float* W2    = (const float*)d_in[9];
    const float* attn2 = (const float*)d_in[10];
    const float* res2  = (const float*)d_in[11];
    const float* bias2 = (const float*)d_in[12];
    const float* nnW2  = (const float*)d_in[13];
    const float* nnb2  = (const float*)d_in[14];
    const float* bn2   = (const float*)d_in[15];
    const int* go_src   = (const int*)d_in[16];
    const int* go_dst   = (const int*)d_in[17];
    const int* back_src = (const int*)d_in[18];
    const int* back_dst = (const int*)d_in[19];

    // workspace layout (~110 MB)
    int* icnt = (int*)d_ws;                    // 2*NN   (hist counts, reused as fill cursors)
    int* ioff = icnt + 2 * NN;                 // 2*(NN+1)
    int* icsr = ioff + 2 * (NN + 1);           // 2*Ec   (src ids sorted by dst)
    float* aw  = (float*)(icsr + 2 * Ec);      // 8*192 attn-reduced weights
    float* fs  = aw + 2048;                    // NN*96
    float* acc = fs + (size_t)NN * HD;         // NN*96
    float* el  = acc + (size_t)NN * HD;        // NN*3
    float* er  = el + (size_t)NN * 3;          // NN*3
    float* hu1 = er + (size_t)NN * 3;          // NN*32
    float* hi1 = hu1 + (size_t)NN * DOUT;      // NN*32

    float* out_user = (float*)d_out;
    float* out_item = out_user + (size_t)NN * DOUT;

    // 1) reduce attention vectors into DINx3 matrices (all 4 relations, both sides)
    {
        const float* Wm[4] = { W1, W1 + 64 * HD, W2, W2 + 32 * HD };
        const float* Am[4] = { attn1, attn1 + 192, attn2, attn2 + 192 };
        const int dins[4] = { 64, 64, 32, 32 };
        AWJobs js;
        for (int r = 0; r < 4; ++r)
            for (int s = 0; s < 2; ++s)
                js.j[r * 2 + s] = { Wm[r], Am[r] + s * HD, aw + (size_t)(r * 2 + s) * 192, dins[r] };
        attw_k<<<8, 192, 0, stream>>>(js);
    }

    // 2) build CSR (dst-sorted) for both relations
    zero_k<<<(2 * NN + 255) / 256, 256, 0, stream>>>(icnt, 2 * NN);
    hist_k<<<(2 * Ec + 255) / 256, 256, 0, stream>>>(go_dst, back_dst, icnt);
    scan_k<<<2, 1024, 0, stream>>>(icnt, ioff);
    fill_k<<<(2 * Ec + 255) / 256, 256, 0, stream>>>(go_src, go_dst, back_src, back_dst, ioff, icnt, icsr);

    auto run_rel = [&](int din, const float* srcX, const float* dstX,
                       const float* W, const float* resW, const float* bias,
                       const float* Wl, const float* Wr,
                       const int* off, const int* csr,
                       const float* lW, const float* lb, const float* bnp, float* outp)
    {
        TJob jA = { srcX, W,    Wl, nullptr, fs,  el };
        TJob jB = { dstX, resW, Wr, bias,    acc, er };
        dim3 g((NN + 127) / 128, 2);
        if (din == 64) transform_k<64><<<g, 128, 0, stream>>>(jA, jB, NN);
        else           transform_k<32><<<g, 128, 0, stream>>>(jA, jB, NN);
        agg_k<<<(NN * 64 + 255) / 256, 256, 0, stream>>>(off, csr, el, er, fs, acc, NN);
        lin_bn_relu_k<<<(NN + 7) / 8, 256, 0, stream>>>(acc, lW, lb, bnp, outp, NN);
    };

    // ---- layer 1 ----
    run_rel(64, emb_user, emb_item, W1,            res1,            bias1,
            aw + 0,    aw + 192,  ioff,          icsr,
            nnW1 + HD * DOUT, nnb1 + DOUT, bn1 + 4 * DOUT, hi1);          // 'go' -> items
    run_rel(64, emb_item, emb_user, W1 + 64 * HD,  res1 + 64 * HD,  bias1 + HD,
            aw + 384,  aw + 576,  ioff + NN + 1, icsr + Ec,
            nnW1, nnb1, bn1, hu1);                                         // 'back' -> users

    // ---- layer 2 ----
    run_rel(32, hu1, hi1, W2,           res2,           bias2,
            aw + 768,  aw + 960,  ioff,          icsr,
            nnW2 + HD * DOUT, nnb2 + DOUT, bn2 + 4 * DOUT, out_item);      // 'go' -> items
    run_rel(32, hi1, hu1, W2 + 32 * HD, res2 + 32 * HD, bias2 + HD,
            aw + 1152, aw + 1344, ioff + NN + 1, icsr + Ec,
            nnW2, nnb2, bn2, out_user);                                    // 'back' -> users
}

// Round 4
// 1092.257 us; speedup vs baseline: 1.8629x; 1.3158x over previous
//
#include <hip/hip_runtime.h>
#include <cmath>

#define NHEAD 3
#define HD 96          // H * D = 3 * 32
#define DOUT 32
#define SLOPE 0.01f
#define BN_EPS 1e-5f

static constexpr int NN = 100000;   // NU == NI == 100000
static constexpr int Ec = 500000;
static constexpr int SCB = (NN + 255) / 256;   // 391 chunks per relation

// ---------------- job structs ----------------
struct TJob { const float* X; const float* W; const float* Wsm; const float* bias; float* outF; float* outE; };
struct AWJob { const float* W; const float* a; float* out; int din; };
struct AWJobs { AWJob j[8]; };

// ---------------- attn-weight pre-reduction: Wl/Wr[k,h] = sum_d W[k, h*32+d] * a[h*32+d] ----------------
__global__ __launch_bounds__(192)
void attw_k(AWJobs js) {
    AWJob jb = js.j[blockIdx.x];
    const int t = threadIdx.x;
    const int k = t / 3, h = t - 3 * (t / 3);
    if (k < jb.din) {
        const float* wrow = jb.W + (size_t)k * HD + h * 32;
        const float* av = jb.a + h * 32;
        float s = 0.f;
        #pragma unroll
        for (int d = 0; d < 32; ++d) s = fmaf(wrow[d], av[d], s);
        jb.out[k * 3 + h] = s;
    }
}

// ---------------- CSR build ----------------
__global__ void zero_k(int* p, int n) {
    const int i = blockIdx.x * 256 + threadIdx.x;
    if (i < n) p[i] = 0;
}

__global__ void hist_k(const int* __restrict__ gd, const int* __restrict__ bd, int* __restrict__ cnt) {
    const int i = blockIdx.x * 256 + threadIdx.x;
    if (i < Ec) atomicAdd(&cnt[gd[i]], 1);
    else if (i < 2 * Ec) atomicAdd(&cnt[NN + bd[i - Ec]], 1);
}

// phase A: per-256-chunk sums  (grid: SCB x 2)
__global__ __launch_bounds__(256)
void scan_a_k(const int* __restrict__ cnt, int* __restrict__ bsum) {
    const int rel = blockIdx.y, blk = blockIdx.x;
    const int i = blk * 256 + threadIdx.x;
    int v = (i < NN) ? cnt[rel * NN + i] : 0;
    #pragma unroll
    for (int d = 32; d; d >>= 1) v += __shfl_xor(v, d);
    __shared__ int ws[4];
    const int lane = threadIdx.x & 63, wid = threadIdx.x >> 6;
    if (lane == 0) ws[wid] = v;
    __syncthreads();
    if (threadIdx.x == 0) bsum[rel * SCB + blk] = ws[0] + ws[1] + ws[2] + ws[3];
}

// phase B: scan the SCB chunk sums per relation (grid: 2 x 512)
__global__ __launch_bounds__(512)
void scan_b_k(int* __restrict__ bsum, int* __restrict__ off) {
    const int rel = blockIdx.x;
    __shared__ int ps[512];
    const int t = threadIdx.x;
    const int v = (t < SCB) ? bsum[rel * SCB + t] : 0;
    ps[t] = v;
    __syncthreads();
    for (int d = 1; d < 512; d <<= 1) {
        const int u = (t >= d) ? ps[t - d] : 0;
        __syncthreads();
        ps[t] += u;
        __syncthreads();
    }
    if (t < SCB) bsum[rel * SCB + t] = ps[t] - v;          // exclusive chunk base
    if (t == SCB - 1) off[rel * (NN + 1) + NN] = ps[t];    // total
}

// phase C: per-chunk exclusive scan + write offsets + zero cursors (grid: SCB x 2)
__global__ __launch_bounds__(256)
void scan_c_k(int* __restrict__ cnt, const int* __restrict__ bsum, int* __restrict__ off) {
    const int rel = blockIdx.y, blk = blockIdx.x;
    const int t = threadIdx.x;
    const int i = blk * 256 + t;
    const int v = (i < NN) ? cnt[rel * NN + i] : 0;
    const int lane = t & 63, wid = t >> 6;
    int incl = v;
    #pragma unroll
    for (int d = 1; d < 64; d <<= 1) {
        const int u = __shfl_up(incl, d);
        if (lane >= d) incl += u;
    }
    __shared__ int wsum[4];
    if (lane == 63) wsum[wid] = incl;
    __syncthreads();
    int base = 0;
    #pragma unroll
    for (int w = 0; w < 4; ++w) base += (w < wid) ? wsum[w] : 0;
    if (i < NN) {
        off[rel * (NN + 1) + i] = bsum[rel * SCB + blk] + base + incl - v;
        cnt[rel * NN + i] = 0;   // reset as fill cursors
    }
}

__global__ void fill_k(const int* __restrict__ gs, const int* __restrict__ gd,
                       const int* __restrict__ bs, const int* __restrict__ bd,
                       const int* __restrict__ off, int* __restrict__ cur, int* __restrict__ csr) {
    const int i = blockIdx.x * 256 + threadIdx.x;
    if (i < Ec) {
        const int d = gd[i];
        const int p = off[d] + atomicAdd(&cur[d], 1);
        csr[p] = gs[i];
    } else if (i < 2 * Ec) {
        const int d = bd[i - Ec];
        const int p = off[(NN + 1) + d] + atomicAdd(&cur[NN + d], 1);
        csr[Ec + p] = bs[i - Ec];
    }
}

// ---------------- dense transform: outF = X@W (+bias), outE = X@Wsm (3 attn dots) ----------------
template<int DIN>
__global__ __launch_bounds__(128)
void transform_k(TJob jA, TJob jB, int N) {
    const TJob j = (blockIdx.y == 0) ? jA : jB;
    __shared__ float Ws[DIN * HD];
    __shared__ float Wsm[DIN * 3];
    __shared__ float Bs[HD];
    __shared__ float Xs[128 * (DIN + 1)];
    const int t = threadIdx.x;
    for (int i = t; i < DIN * HD; i += 128) Ws[i] = j.W[i];
    for (int i = t; i < DIN * 3; i += 128) Wsm[i] = j.Wsm[i];
    if (t < HD) Bs[t] = j.bias ? j.bias[t] : 0.f;
    const int base = blockIdx.x * 128;
    const int nv = min(128, N - base);
    for (int i = t; i < nv * DIN; i += 128) {
        const int r = i / DIN, c = i - r * DIN;
        Xs[r * (DIN + 1) + c] = j.X[(size_t)base * DIN + i];   // coalesced
    }
    __syncthreads();
    if (t >= nv) return;

    float xr[DIN];
    #pragma unroll
    for (int k = 0; k < DIN; ++k) xr[k] = Xs[t * (DIN + 1) + k];
    const size_t n = (size_t)(base + t);

    float e0 = 0.f, e1 = 0.f, e2 = 0.f;
    #pragma unroll
    for (int k = 0; k < DIN; ++k) {
        e0 = fmaf(xr[k], Wsm[k * 3 + 0], e0);
        e1 = fmaf(xr[k], Wsm[k * 3 + 1], e1);
        e2 = fmaf(xr[k], Wsm[k * 3 + 2], e2);
    }
    j.outE[n * 3 + 0] = e0; j.outE[n * 3 + 1] = e1; j.outE[n * 3 + 2] = e2;

    for (int jo = 0; jo < HD; jo += 4) {
        float a0 = Bs[jo], a1 = Bs[jo + 1], a2 = Bs[jo + 2], a3 = Bs[jo + 3];
        #pragma unroll
        for (int k = 0; k < DIN; ++k) {
            const float4 w = *reinterpret_cast<const float4*>(&Ws[k * HD + jo]);
            const float x = xr[k];
            a0 = fmaf(x, w.x, a0); a1 = fmaf(x, w.y, a1);
            a2 = fmaf(x, w.z, a2); a3 = fmaf(x, w.w, a3);
        }
        float4 o; o.x = a0; o.y = a1; o.z = a2; o.w = a3;
        *reinterpret_cast<float4*>(&j.outF[n * HD + jo]) = o;
    }
}

// ---------------- fused softmax + aggregation: one wave per dst node ----------------
__global__ __launch_bounds__(256)
void agg_k(const int* __restrict__ off, const int* __restrict__ srcs,
           const float* __restrict__ el, const float* __restrict__ er,
           const float* __restrict__ fs, float* __restrict__ acc, int N)
{
    const int node = (int)((blockIdx.x * 256u + threadIdx.x) >> 6);
    const int lane = threadIdx.x & 63;
    if (node >= N) return;
    const int o0 = off[node], o1 = off[node + 1];
    const int deg = o1 - o0;
    const float er0 = er[node * 3 + 0], er1 = er[node * 3 + 1], er2 = er[node * 3 + 2];
    const int h = lane >> 5;
    const size_t ab = (size_t)node * HD;
    float a0 = 0.f, a1 = 0.f;

    if (deg <= 64) {
        // ---- register-resident fast path: 1 edge per lane ----
        const int p = o0 + lane;
        const bool has = p < o1;
        const int s = has ? srcs[p] : 0;
        float v0 = -INFINITY, v1 = -INFINITY, v2 = -INFINITY;
        if (has) {
            v0 = el[s * 3 + 0] + er0; v0 = v0 > 0.f ? v0 : SLOPE * v0;
            v1 = el[s * 3 + 1] + er1; v1 = v1 > 0.f ? v1 : SLOPE * v1;
            v2 = el[s * 3 + 2] + er2; v2 = v2 > 0.f ? v2 : SLOPE * v2;
        }
        float m0 = v0, m1 = v1, m2 = v2;
        #pragma unroll
        for (int d = 32; d; d >>= 1) {
            m0 = fmaxf(m0, __shfl_xor(m0, d));
            m1 = fmaxf(m1, __shfl_xor(m1, d));
            m2 = fmaxf(m2, __shfl_xor(m2, d));
        }
        float e0 = has ? __expf(v0 - m0) : 0.f;
        float e1 = has ? __expf(v1 - m1) : 0.f;
        float e2 = has ? __expf(v2 - m2) : 0.f;
        float s0 = e0, s1 = e1, s2 = e2;
        #pragma unroll
        for (int d = 32; d; d >>= 1) {
            s0 += __shfl_xor(s0, d); s1 += __shfl_xor(s1, d); s2 += __shfl_xor(s2, d);
        }
        const float w0 = e0 * (s0 > 0.f ? 1.f / s0 : 0.f);
        const float w1 = e1 * (s1 > 0.f ? 1.f / s1 : 0.f);
        const float w2 = e2 * (s2 > 0.f ? 1.f / s2 : 0.f);
        // serial over edges; index+weight via shfl (no dependent loads)
        for (int jj = 0; jj < deg; ++jj) {
            const int sj = __shfl(s, jj);
            const float t0 = __shfl(w0, jj), t1 = __shfl(w1, jj), t2 = __shfl(w2, jj);
            const size_t fb = (size_t)sj * HD;
            a0 = fmaf(fs[fb + lane], h ? t1 : t0, a0);
            if (lane < 32) a1 = fmaf(fs[fb + 64 + lane], t2, a1);
        }
    } else {
        // ---- generic path (deg > 64) ----
        float m0 = -INFINITY, m1 = -INFINITY, m2 = -INFINITY;
        for (int p = o0 + lane; p < o1; p += 64) {
            const int s = srcs[p];
            float v0 = el[s * 3 + 0] + er0; v0 = v0 > 0.f ? v0 : SLOPE * v0;
            float v1 = el[s * 3 + 1] + er1; v1 = v1 > 0.f ? v1 : SLOPE * v1;
            float v2 = el[s * 3 + 2] + er2; v2 = v2 > 0.f ? v2 : SLOPE * v2;
            m0 = fmaxf(m0, v0); m1 = fmaxf(m1, v1); m2 = fmaxf(m2, v2);
        }
        #pragma unroll
        for (int d = 32; d; d >>= 1) {
            m0 = fmaxf(m0, __shfl_xor(m0, d));
            m1 = fmaxf(m1, __shfl_xor(m1, d));
            m2 = fmaxf(m2, __shfl_xor(m2, d));
        }
        float s0 = 0.f, s1 = 0.f, s2 = 0.f;
        for (int p = o0 + lane; p < o1; p += 64) {
            const int s = srcs[p];
            float v0 = el[s * 3 + 0] + er0; v0 = v0 > 0.f ? v0 : SLOPE * v0;
            float v1 = el[s * 3 + 1] + er1; v1 = v1 > 0.f ? v1 : SLOPE * v1;
            float v2 = el[s * 3 + 2] + er2; v2 = v2 > 0.f ? v2 : SLOPE * v2;
            s0 += __expf(v0 - m0); s1 += __expf(v1 - m1); s2 += __expf(v2 - m2);
        }
        #pragma unroll
        for (int d = 32; d; d >>= 1) {
            s0 += __shfl_xor(s0, d); s1 += __shfl_xor(s1, d); s2 += __shfl_xor(s2, d);
        }
        const float r0 = s0 > 0.f ? 1.f / s0 : 0.f;
        const float r1 = s1 > 0.f ? 1.f / s1 : 0.f;
        const float r2 = s2 > 0.f ? 1.f / s2 : 0.f;
        const float erh = h ? er1 : er0;
        const float mh  = h ? m1  : m0;
        const float rh  = h ? r1  : r0;
        for (int p = o0; p < o1; ++p) {
            const int s = srcs[p];
            float v = el[s * 3 + h] + erh; v = v > 0.f ? v : SLOPE * v;
            const float w = __expf(v - mh) * rh;
            float v2 = el[s * 3 + 2] + er2; v2 = v2 > 0.f ? v2 : SLOPE * v2;
            const float w2 = __expf(v2 - m2) * r2;
            const size_t fb = (size_t)s * HD;
            a0 = fmaf(fs[fb + lane], w, a0);
            if (lane < 32) a1 = fmaf(fs[fb + 64 + lane], w2, a1);
        }
    }
    acc[ab + lane] += a0;                          // acc holds res + bias
    if (lane < 32) acc[ab + 64 + lane] += a1;
}

// ---------------- linear + BN(eval) + ReLU ----------------
__global__ __launch_bounds__(256)
void lin_bn_relu_k(const float* __restrict__ X, const float* __restrict__ Wl,
                   const float* __restrict__ bl, const float* __restrict__ bn,
                   float* __restrict__ out, int N)
{
    __shared__ float Ws[HD * DOUT];
    const int t = threadIdx.x;
    for (int i = t; i < HD * DOUT; i += 256) Ws[i] = Wl[i];
    __syncthreads();
    const int o = t & 31, ln = t >> 5;
    const int n = blockIdx.x * 8 + ln;
    if (n >= N) return;
    float acc = bl[o];
    const float* xrow = X + (size_t)n * HD;
    #pragma unroll
    for (int k4 = 0; k4 < HD; k4 += 4) {
        const float4 xv = *reinterpret_cast<const float4*>(xrow + k4);
        acc = fmaf(xv.x, Ws[(k4    ) * DOUT + o], acc);
        acc = fmaf(xv.y, Ws[(k4 + 1) * DOUT + o], acc);
        acc = fmaf(xv.z, Ws[(k4 + 2) * DOUT + o], acc);
        acc = fmaf(xv.w, Ws[(k4 + 3) * DOUT + o], acc);
    }
    const float gamma = bn[o], beta = bn[DOUT + o], mean = bn[2 * DOUT + o], var = bn[3 * DOUT + o];
    const float y = (acc - mean) * gamma * rsqrtf(var + BN_EPS) + beta;
    out[(size_t)n * DOUT + o] = fmaxf(y, 0.f);
}

// ---------------- host ----------------
extern "C" void kernel_launch(void* const* d_in, const int* in_sizes, int n_in,
                              void* d_out, int out_size, void* d_ws, size_t ws_size,
                              hipStream_t stream)
{
    const float* emb_user = (const float*)d_in[0];
    const float* emb_item = (const float*)d_in[1];
    const float* W1    = (const float*)d_in[2];
    const float* attn1 = (const float*)d_in[3];
    const float* res1  = (const float*)d_in[4];
    const float* bias1 = (const float*)d_in[5];
    const float* nnW1  = (const float*)d_in[6];
    const float* nnb1  = (const float*)d_in[7];
    const float* bn1   = (const float*)d_in[8];
    const float* W2    = (const float*)d_in[9];
    const float* attn2 = (const float*)d_in[10];
    const float* res2  = (const float*)d_in[11];
    const float* bias2 = (const float*)d_in[12];
    const float* nnW2  = (const float*)d_in[13];
    const float* nnb2  = (const float*)d_in[14];
    const float* bn2   = (const float*)d_in[15];
    const int* go_src   = (const int*)d_in[16];
    const int* go_dst   = (const int*)d_in[17];
    const int* back_src = (const int*)d_in[18];
    const int* back_dst = (const int*)d_in[19];

    // workspace layout (~110 MB)
    int* icnt = (int*)d_ws;                    // 2*NN   (hist counts, reused as fill cursors)
    int* ioff = icnt + 2 * NN;                 // 2*(NN+1)
    int* icsr = ioff + 2 * (NN + 1);           // 2*Ec
    int* ibs  = icsr + 2 * Ec;                 // 2*SCB chunk sums (782)
    float* aw  = (float*)(icsr + 2 * Ec + 784);// keep fs 16B-aligned: 1400784+784? -> recompute below
    // total ints so far: 200000 + 200002 + 1000000 + 782 = 1400784; pad to 1400800 (x4B = 16B-aligned)
    aw = (float*)((int*)d_ws + 1400800);       // 8*192 attn-reduced weights (1536) + pad 512 -> 2048
    float* fs  = aw + 2048;                    // NN*96
    float* acc = fs + (size_t)NN * HD;         // NN*96
    float* el  = acc + (size_t)NN * HD;        // NN*3
    float* er  = el + (size_t)NN * 3;          // NN*3
    float* hu1 = er + (size_t)NN * 3;          // NN*32
    float* hi1 = hu1 + (size_t)NN * DOUT;      // NN*32

    float* out_user = (float*)d_out;
    float* out_item = out_user + (size_t)NN * DOUT;

    // 1) reduce attention vectors into DINx3 matrices (all 4 relations, both sides)
    {
        const float* Wm[4] = { W1, W1 + 64 * HD, W2, W2 + 32 * HD };
        const float* Am[4] = { attn1, attn1 + 192, attn2, attn2 + 192 };
        const int dins[4] = { 64, 64, 32, 32 };
        AWJobs js;
        for (int r = 0; r < 4; ++r)
            for (int s = 0; s < 2; ++s)
                js.j[r * 2 + s] = { Wm[r], Am[r] + s * HD, aw + (size_t)(r * 2 + s) * 192, dins[r] };
        attw_k<<<8, 192, 0, stream>>>(js);
    }

    // 2) build CSR (dst-sorted) for both relations — fully parallel scan
    zero_k<<<(2 * NN + 255) / 256, 256, 0, stream>>>(icnt, 2 * NN);
    hist_k<<<(2 * Ec + 255) / 256, 256, 0, stream>>>(go_dst, back_dst, icnt);
    scan_a_k<<<dim3(SCB, 2), 256, 0, stream>>>(icnt, ibs);
    scan_b_k<<<2, 512, 0, stream>>>(ibs, ioff);
    scan_c_k<<<dim3(SCB, 2), 256, 0, stream>>>(icnt, ibs, ioff);
    fill_k<<<(2 * Ec + 255) / 256, 256, 0, stream>>>(go_src, go_dst, back_src, back_dst, ioff, icnt, icsr);

    auto run_rel = [&](int din, const float* srcX, const float* dstX,
                       const float* W, const float* resW, const float* bias,
                       const float* Wl, const float* Wr,
                       const int* off, const int* csr,
                       const float* lW, const float* lb, const float* bnp, float* outp)
    {
        TJob jA = { srcX, W,    Wl, nullptr, fs,  el };
        TJob jB = { dstX, resW, Wr, bias,    acc, er };
        dim3 g((NN + 127) / 128, 2);
        if (din == 64) transform_k<64><<<g, 128, 0, stream>>>(jA, jB, NN);
        else           transform_k<32><<<g, 128, 0, stream>>>(jA, jB, NN);
        agg_k<<<(NN * 64 + 255) / 256, 256, 0, stream>>>(off, csr, el, er, fs, acc, NN);
        lin_bn_relu_k<<<(NN + 7) / 8, 256, 0, stream>>>(acc, lW, lb, bnp, outp, NN);
    };

    // ---- layer 1 ----
    run_rel(64, emb_user, emb_item, W1,            res1,            bias1,
            aw + 0,    aw + 192,  ioff,          icsr,
            nnW1 + HD * DOUT, nnb1 + DOUT, bn1 + 4 * DOUT, hi1);          // 'go' -> items
    run_rel(64, emb_item, emb_user, W1 + 64 * HD,  res1 + 64 * HD,  bias1 + HD,
            aw + 384,  aw + 576,  ioff + NN + 1, icsr + Ec,
            nnW1, nnb1, bn1, hu1);                                         // 'back' -> users

    // ---- layer 2 ----
    run_rel(32, hu1, hi1, W2,           res2,           bias2,
            aw + 768,  aw + 960,  ioff,          icsr,
            nnW2 + HD * DOUT, nnb2 + DOUT, bn2 + 4 * DOUT, out_item);      // 'go' -> items
    run_rel(32, hi1, hu1, W2 + 32 * HD, res2 + 32 * HD, bias2 + HD,
            aw + 1152, aw + 1344, ioff + NN + 1, icsr + Ec,
            nnW2, nnb2, bn2, out_user);                                    // 'back' -> users

    (void)ibs;
}

// Round 5
// 855.608 us; speedup vs baseline: 2.3782x; 1.2766x over previous
//
#include <hip/hip_runtime.h>
#include <cmath>

#define NHEAD 3
#define HD 96          // H * D = 3 * 32
#define DOUT 32
#define SLOPE 0.01f
#define BN_EPS 1e-5f

static constexpr int NN = 100000;   // NU == NI == 100000
static constexpr int Ec = 500000;
static constexpr int SCB = (NN + 255) / 256;   // 391 chunks per relation

// ---------------- job structs ----------------
struct TJob { const float* X; const float* W; const float* Wsm; const float* bias; float* outF; float* outE; };
struct AWJob { const float* W; const float* a; float* out; int din; };
struct AWJobs { AWJob j[8]; };

// ---------------- attn-weight pre-reduction: Wl/Wr[k,h] = sum_d W[k, h*32+d] * a[h*32+d] ----------------
__global__ __launch_bounds__(192)
void attw_k(AWJobs js) {
    AWJob jb = js.j[blockIdx.x];
    const int t = threadIdx.x;
    const int k = t / 3, h = t - 3 * (t / 3);
    if (k < jb.din) {
        const float* wrow = jb.W + (size_t)k * HD + h * 32;
        const float* av = jb.a + h * 32;
        float s = 0.f;
        #pragma unroll
        for (int d = 0; d < 32; ++d) s = fmaf(wrow[d], av[d], s);
        jb.out[k * 3 + h] = s;
    }
}

// ---------------- CSR build ----------------
__global__ void zero_k(int* p, int n) {
    const int i = blockIdx.x * 256 + threadIdx.x;
    if (i < n) p[i] = 0;
}

__global__ void hist_k(const int* __restrict__ gd, const int* __restrict__ bd, int* __restrict__ cnt) {
    const int i = blockIdx.x * 256 + threadIdx.x;
    if (i < Ec) atomicAdd(&cnt[gd[i]], 1);
    else if (i < 2 * Ec) atomicAdd(&cnt[NN + bd[i - Ec]], 1);
}

// phase A: per-256-chunk sums  (grid: SCB x 2)
__global__ __launch_bounds__(256)
void scan_a_k(const int* __restrict__ cnt, int* __restrict__ bsum) {
    const int rel = blockIdx.y, blk = blockIdx.x;
    const int i = blk * 256 + threadIdx.x;
    int v = (i < NN) ? cnt[rel * NN + i] : 0;
    #pragma unroll
    for (int d = 32; d; d >>= 1) v += __shfl_xor(v, d);
    __shared__ int ws[4];
    const int lane = threadIdx.x & 63, wid = threadIdx.x >> 6;
    if (lane == 0) ws[wid] = v;
    __syncthreads();
    if (threadIdx.x == 0) bsum[rel * SCB + blk] = ws[0] + ws[1] + ws[2] + ws[3];
}

// phase B: scan the SCB chunk sums per relation (grid: 2 x 512)
__global__ __launch_bounds__(512)
void scan_b_k(int* __restrict__ bsum, int* __restrict__ off) {
    const int rel = blockIdx.x;
    __shared__ int ps[512];
    const int t = threadIdx.x;
    const int v = (t < SCB) ? bsum[rel * SCB + t] : 0;
    ps[t] = v;
    __syncthreads();
    for (int d = 1; d < 512; d <<= 1) {
        const int u = (t >= d) ? ps[t - d] : 0;
        __syncthreads();
        ps[t] += u;
        __syncthreads();
    }
    if (t < SCB) bsum[rel * SCB + t] = ps[t] - v;          // exclusive chunk base
    if (t == SCB - 1) off[rel * (NN + 1) + NN] = ps[t];    // total
}

// phase C: per-chunk exclusive scan + write offsets + zero cursors (grid: SCB x 2)
__global__ __launch_bounds__(256)
void scan_c_k(int* __restrict__ cnt, const int* __restrict__ bsum, int* __restrict__ off) {
    const int rel = blockIdx.y, blk = blockIdx.x;
    const int t = threadIdx.x;
    const int i = blk * 256 + t;
    const int v = (i < NN) ? cnt[rel * NN + i] : 0;
    const int lane = t & 63, wid = t >> 6;
    int incl = v;
    #pragma unroll
    for (int d = 1; d < 64; d <<= 1) {
        const int u = __shfl_up(incl, d);
        if (lane >= d) incl += u;
    }
    __shared__ int wsum[4];
    if (lane == 63) wsum[wid] = incl;
    __syncthreads();
    int base = 0;
    #pragma unroll
    for (int w = 0; w < 4; ++w) base += (w < wid) ? wsum[w] : 0;
    if (i < NN) {
        off[rel * (NN + 1) + i] = bsum[rel * SCB + blk] + base + incl - v;
        cnt[rel * NN + i] = 0;   // reset as fill cursors
    }
}

__global__ void fill_k(const int* __restrict__ gs, const int* __restrict__ gd,
                       const int* __restrict__ bs, const int* __restrict__ bd,
                       const int* __restrict__ off, int* __restrict__ cur, int* __restrict__ csr) {
    const int i = blockIdx.x * 256 + threadIdx.x;
    if (i < Ec) {
        const int d = gd[i];
        const int p = off[d] + atomicAdd(&cur[d], 1);
        csr[p] = gs[i];
    } else if (i < 2 * Ec) {
        const int d = bd[i - Ec];
        const int p = off[(NN + 1) + d] + atomicAdd(&cur[NN + d], 1);
        csr[Ec + p] = bs[i - Ec];
    }
}

// ---------------- dense transform v2: node-per-thread, acc in VGPRs, W via uniform scalar loads ----------------
// outF = X@W (+bias), outE = X@Wsm. No LDS. W index is thread-uniform -> s_load; FMA is VGPR x SGPR.
template<int DIN>
__global__ __launch_bounds__(256)
void transform_k(TJob jA, TJob jB, int N) {
    const TJob j = (blockIdx.y == 0) ? jA : jB;
    const int n = blockIdx.x * 256 + threadIdx.x;
    if (n >= N) return;
    const float* __restrict__ Wg  = j.W;
    const float* __restrict__ Wsm = j.Wsm;
    const float* __restrict__ bs  = j.bias;

    float acc[HD];
    if (bs) {
        #pragma unroll
        for (int jo = 0; jo < HD; ++jo) acc[jo] = bs[jo];     // uniform -> s_load
    } else {
        #pragma unroll
        for (int jo = 0; jo < HD; ++jo) acc[jo] = 0.f;
    }
    float e0 = 0.f, e1 = 0.f, e2 = 0.f;

    const float4* __restrict__ xrow = reinterpret_cast<const float4*>(j.X + (size_t)n * DIN);
    #pragma unroll 1
    for (int kk = 0; kk < DIN / 4; ++kk) {
        const float4 xv = xrow[kk];
        float xs[4] = { xv.x, xv.y, xv.z, xv.w };
        #pragma unroll
        for (int q = 0; q < 4; ++q) {
            const int k = kk * 4 + q;
            const float x = xs[q];
            e0 = fmaf(x, Wsm[k * 3 + 0], e0);
            e1 = fmaf(x, Wsm[k * 3 + 1], e1);
            e2 = fmaf(x, Wsm[k * 3 + 2], e2);
            #pragma unroll
            for (int jo = 0; jo < HD; ++jo)
                acc[jo] = fmaf(x, Wg[k * HD + jo], acc[jo]);  // Wg idx uniform -> s_load
        }
    }
    j.outE[(size_t)n * 3 + 0] = e0;
    j.outE[(size_t)n * 3 + 1] = e1;
    j.outE[(size_t)n * 3 + 2] = e2;
    float* __restrict__ op = j.outF + (size_t)n * HD;
    #pragma unroll
    for (int jo = 0; jo < HD; jo += 4) {
        float4 o; o.x = acc[jo]; o.y = acc[jo + 1]; o.z = acc[jo + 2]; o.w = acc[jo + 3];
        *reinterpret_cast<float4*>(op + jo) = o;
    }
}

// ---------------- fused softmax + aggregation: one wave per dst node ----------------
__global__ __launch_bounds__(256)
void agg_k(const int* __restrict__ off, const int* __restrict__ srcs,
           const float* __restrict__ el, const float* __restrict__ er,
           const float* __restrict__ fs, float* __restrict__ acc, int N)
{
    const int node = (int)((blockIdx.x * 256u + threadIdx.x) >> 6);
    const int lane = threadIdx.x & 63;
    if (node >= N) return;
    const int o0 = off[node], o1 = off[node + 1];
    const int deg = o1 - o0;
    const float er0 = er[node * 3 + 0], er1 = er[node * 3 + 1], er2 = er[node * 3 + 2];
    const int h = lane >> 5;
    const size_t ab = (size_t)node * HD;
    float a0 = 0.f, a1 = 0.f;

    if (deg <= 64) {
        // ---- register-resident fast path: 1 edge per lane ----
        const int p = o0 + lane;
        const bool has = p < o1;
        const int s = has ? srcs[p] : 0;
        float v0 = -INFINITY, v1 = -INFINITY, v2 = -INFINITY;
        if (has) {
            v0 = el[s * 3 + 0] + er0; v0 = v0 > 0.f ? v0 : SLOPE * v0;
            v1 = el[s * 3 + 1] + er1; v1 = v1 > 0.f ? v1 : SLOPE * v1;
            v2 = el[s * 3 + 2] + er2; v2 = v2 > 0.f ? v2 : SLOPE * v2;
        }
        float m0 = v0, m1 = v1, m2 = v2;
        #pragma unroll
        for (int d = 32; d; d >>= 1) {
            m0 = fmaxf(m0, __shfl_xor(m0, d));
            m1 = fmaxf(m1, __shfl_xor(m1, d));
            m2 = fmaxf(m2, __shfl_xor(m2, d));
        }
        float e0 = has ? __expf(v0 - m0) : 0.f;
        float e1 = has ? __expf(v1 - m1) : 0.f;
        float e2 = has ? __expf(v2 - m2) : 0.f;
        float s0 = e0, s1 = e1, s2 = e2;
        #pragma unroll
        for (int d = 32; d; d >>= 1) {
            s0 += __shfl_xor(s0, d); s1 += __shfl_xor(s1, d); s2 += __shfl_xor(s2, d);
        }
        const float w0 = e0 * (s0 > 0.f ? 1.f / s0 : 0.f);
        const float w1 = e1 * (s1 > 0.f ? 1.f / s1 : 0.f);
        const float w2 = e2 * (s2 > 0.f ? 1.f / s2 : 0.f);
        // serial over edges; index+weight via shfl (no dependent loads)
        for (int jj = 0; jj < deg; ++jj) {
            const int sj = __shfl(s, jj);
            const float t0 = __shfl(w0, jj), t1 = __shfl(w1, jj), t2 = __shfl(w2, jj);
            const size_t fb = (size_t)sj * HD;
            a0 = fmaf(fs[fb + lane], h ? t1 : t0, a0);
            if (lane < 32) a1 = fmaf(fs[fb + 64 + lane], t2, a1);
        }
    } else {
        // ---- generic path (deg > 64) ----
        float m0 = -INFINITY, m1 = -INFINITY, m2 = -INFINITY;
        for (int p = o0 + lane; p < o1; p += 64) {
            const int s = srcs[p];
            float v0 = el[s * 3 + 0] + er0; v0 = v0 > 0.f ? v0 : SLOPE * v0;
            float v1 = el[s * 3 + 1] + er1; v1 = v1 > 0.f ? v1 : SLOPE * v1;
            float v2 = el[s * 3 + 2] + er2; v2 = v2 > 0.f ? v2 : SLOPE * v2;
            m0 = fmaxf(m0, v0); m1 = fmaxf(m1, v1); m2 = fmaxf(m2, v2);
        }
        #pragma unroll
        for (int d = 32; d; d >>= 1) {
            m0 = fmaxf(m0, __shfl_xor(m0, d));
            m1 = fmaxf(m1, __shfl_xor(m1, d));
            m2 = fmaxf(m2, __shfl_xor(m2, d));
        }
        float s0 = 0.f, s1 = 0.f, s2 = 0.f;
        for (int p = o0 + lane; p < o1; p += 64) {
            const int s = srcs[p];
            float v0 = el[s * 3 + 0] + er0; v0 = v0 > 0.f ? v0 : SLOPE * v0;
            float v1 = el[s * 3 + 1] + er1; v1 = v1 > 0.f ? v1 : SLOPE * v1;
            float v2 = el[s * 3 + 2] + er2; v2 = v2 > 0.f ? v2 : SLOPE * v2;
            s0 += __expf(v0 - m0); s1 += __expf(v1 - m1); s2 += __expf(v2 - m2);
        }
        #pragma unroll
        for (int d = 32; d; d >>= 1) {
            s0 += __shfl_xor(s0, d); s1 += __shfl_xor(s1, d); s2 += __shfl_xor(s2, d);
        }
        const float r0 = s0 > 0.f ? 1.f / s0 : 0.f;
        const float r1 = s1 > 0.f ? 1.f / s1 : 0.f;
        const float r2 = s2 > 0.f ? 1.f / s2 : 0.f;
        const float erh = h ? er1 : er0;
        const float mh  = h ? m1  : m0;
        const float rh  = h ? r1  : r0;
        for (int p = o0; p < o1; ++p) {
            const int s = srcs[p];
            float v = el[s * 3 + h] + erh; v = v > 0.f ? v : SLOPE * v;
            const float w = __expf(v - mh) * rh;
            float v2 = el[s * 3 + 2] + er2; v2 = v2 > 0.f ? v2 : SLOPE * v2;
            const float w2 = __expf(v2 - m2) * r2;
            const size_t fb = (size_t)s * HD;
            a0 = fmaf(fs[fb + lane], w, a0);
            if (lane < 32) a1 = fmaf(fs[fb + 64 + lane], w2, a1);
        }
    }
    acc[ab + lane] += a0;                          // acc holds res + bias
    if (lane < 32) acc[ab + 64 + lane] += a1;
}

// ---------------- linear + BN(eval) + ReLU v2: node-per-thread, W via uniform scalar loads ----------------
__global__ __launch_bounds__(256)
void lin_bn_relu_k(const float* __restrict__ X, const float* __restrict__ Wl,
                   const float* __restrict__ bl, const float* __restrict__ bn,
                   float* __restrict__ out, int N)
{
    const int n = blockIdx.x * 256 + threadIdx.x;
    if (n >= N) return;
    float acc[DOUT];
    #pragma unroll
    for (int o = 0; o < DOUT; ++o) acc[o] = bl[o];            // uniform -> s_load
    const float4* __restrict__ xrow = reinterpret_cast<const float4*>(X + (size_t)n * HD);
    #pragma unroll 1
    for (int kk = 0; kk < HD / 4; ++kk) {
        const float4 xv = xrow[kk];
        float xs[4] = { xv.x, xv.y, xv.z, xv.w };
        #pragma unroll
        for (int q = 0; q < 4; ++q) {
            const float x = xs[q];
            const int k = kk * 4 + q;
            #pragma unroll
            for (int o = 0; o < DOUT; ++o)
                acc[o] = fmaf(x, Wl[k * DOUT + o], acc[o]);   // uniform -> s_load
        }
    }
    float* __restrict__ op = out + (size_t)n * DOUT;
    #pragma unroll
    for (int o = 0; o < DOUT; o += 4) {
        float4 r;
        float* rp = &r.x;
        #pragma unroll
        for (int q = 0; q < 4; ++q) {
            const int oo = o + q;
            const float gamma = bn[oo], beta = bn[DOUT + oo], mean = bn[2 * DOUT + oo], var = bn[3 * DOUT + oo];
            const float y = (acc[oo] - mean) * gamma * rsqrtf(var + BN_EPS) + beta;
            rp[q] = fmaxf(y, 0.f);
        }
        *reinterpret_cast<float4*>(op + o) = r;
    }
}

// ---------------- host ----------------
extern "C" void kernel_launch(void* const* d_in, const int* in_sizes, int n_in,
                              void* d_out, int out_size, void* d_ws, size_t ws_size,
                              hipStream_t stream)
{
    const float* emb_user = (const float*)d_in[0];
    const float* emb_item = (const float*)d_in[1];
    const float* W1    = (const float*)d_in[2];
    const float* attn1 = (const float*)d_in[3];
    const float* res1  = (const float*)d_in[4];
    const float* bias1 = (const float*)d_in[5];
    const float* nnW1  = (const float*)d_in[6];
    const float* nnb1  = (const float*)d_in[7];
    const float* bn1   = (const float*)d_in[8];
    const float* W2    = (const float*)d_in[9];
    const float* attn2 = (const float*)d_in[10];
    const float* res2  = (const float*)d_in[11];
    const float* bias2 = (const float*)d_in[12];
    const float* nnW2  = (const float*)d_in[13];
    const float* nnb2  = (const float*)d_in[14];
    const float* bn2   = (const float*)d_in[15];
    const int* go_src   = (const int*)d_in[16];
    const int* go_dst   = (const int*)d_in[17];
    const int* back_src = (const int*)d_in[18];
    const int* back_dst = (const int*)d_in[19];

    // workspace layout (~110 MB)
    int* icnt = (int*)d_ws;                    // 2*NN   (hist counts, reused as fill cursors)
    int* ioff = icnt + 2 * NN;                 // 2*(NN+1)
    int* icsr = ioff + 2 * (NN + 1);           // 2*Ec
    int* ibs  = icsr + 2 * Ec;                 // 2*SCB chunk sums (782)
    float* aw = (float*)((int*)d_ws + 1400800);// ints padded to 16B boundary; 8*192 attn weights
    float* fs  = aw + 2048;                    // NN*96
    float* acc = fs + (size_t)NN * HD;         // NN*96
    float* el  = acc + (size_t)NN * HD;        // NN*3
    float* er  = el + (size_t)NN * 3;          // NN*3
    float* hu1 = er + (size_t)NN * 3;          // NN*32
    float* hi1 = hu1 + (size_t)NN * DOUT;      // NN*32

    float* out_user = (float*)d_out;
    float* out_item = out_user + (size_t)NN * DOUT;

    // 1) reduce attention vectors into DINx3 matrices (all 4 relations, both sides)
    {
        const float* Wm[4] = { W1, W1 + 64 * HD, W2, W2 + 32 * HD };
        const float* Am[4] = { attn1, attn1 + 192, attn2, attn2 + 192 };
        const int dins[4] = { 64, 64, 32, 32 };
        AWJobs js;
        for (int r = 0; r < 4; ++r)
            for (int s = 0; s < 2; ++s)
                js.j[r * 2 + s] = { Wm[r], Am[r] + s * HD, aw + (size_t)(r * 2 + s) * 192, dins[r] };
        attw_k<<<8, 192, 0, stream>>>(js);
    }

    // 2) build CSR (dst-sorted) for both relations — fully parallel scan
    zero_k<<<(2 * NN + 255) / 256, 256, 0, stream>>>(icnt, 2 * NN);
    hist_k<<<(2 * Ec + 255) / 256, 256, 0, stream>>>(go_dst, back_dst, icnt);
    scan_a_k<<<dim3(SCB, 2), 256, 0, stream>>>(icnt, ibs);
    scan_b_k<<<2, 512, 0, stream>>>(ibs, ioff);
    scan_c_k<<<dim3(SCB, 2), 256, 0, stream>>>(icnt, ibs, ioff);
    fill_k<<<(2 * Ec + 255) / 256, 256, 0, stream>>>(go_src, go_dst, back_src, back_dst, ioff, icnt, icsr);

    auto run_rel = [&](int din, const float* srcX, const float* dstX,
                       const float* W, const float* resW, const float* bias,
                       const float* Wl, const float* Wr,
                       const int* off, const int* csr,
                       const float* lW, const float* lb, const float* bnp, float* outp)
    {
        TJob jA = { srcX, W,    Wl, nullptr, fs,  el };
        TJob jB = { dstX, resW, Wr, bias,    acc, er };
        dim3 g((NN + 255) / 256, 2);
        if (din == 64) transform_k<64><<<g, 256, 0, stream>>>(jA, jB, NN);
        else           transform_k<32><<<g, 256, 0, stream>>>(jA, jB, NN);
        agg_k<<<(NN * 64 + 255) / 256, 256, 0, stream>>>(off, csr, el, er, fs, acc, NN);
        lin_bn_relu_k<<<(NN + 255) / 256, 256, 0, stream>>>(acc, lW, lb, bnp, outp, NN);
    };

    // ---- layer 1 ----
    run_rel(64, emb_user, emb_item, W1,            res1,            bias1,
            aw + 0,    aw + 192,  ioff,          icsr,
            nnW1 + HD * DOUT, nnb1 + DOUT, bn1 + 4 * DOUT, hi1);          // 'go' -> items
    run_rel(64, emb_item, emb_user, W1 + 64 * HD,  res1 + 64 * HD,  bias1 + HD,
            aw + 384,  aw + 576,  ioff + NN + 1, icsr + Ec,
            nnW1, nnb1, bn1, hu1);                                         // 'back' -> users

    // ---- layer 2 ----
    run_rel(32, hu1, hi1, W2,           res2,           bias2,
            aw + 768,  aw + 960,  ioff,          icsr,
            nnW2 + HD * DOUT, nnb2 + DOUT, bn2 + 4 * DOUT, out_item);      // 'go' -> items
    run_rel(32, hi1, hu1, W2 + 32 * HD, res2 + 32 * HD, bias2 + HD,
            aw + 1152, aw + 1344, ioff + NN + 1, icsr + Ec,
            nnW2, nnb2, bn2, out_user);                                    // 'back' -> users

    (void)ibs;
}

// Round 6
// 849.810 us; speedup vs baseline: 2.3944x; 1.0068x over previous
//
#include <hip/hip_runtime.h>
#include <hip/hip_fp16.h>
#include <cmath>

#define NHEAD 3
#define HD 96          // H * D = 3 * 32
#define DOUT 32
#define SLOPE 0.01f
#define BN_EPS 1e-5f

static constexpr int NN = 100000;   // NU == NI == 100000
static constexpr int Ec = 500000;
static constexpr int SCB = (NN + 255) / 256;   // 391 chunks per relation

// ---------------- job structs ----------------
struct TJob { const float* X; const float* W; const float* Wsm; const float* bias; void* outF; float* outE; };
struct AWJob { const float* W; const float* a; float* out; int din; };
struct AWJobs { AWJob j[8]; };

// ---------------- attn-weight pre-reduction ----------------
__global__ __launch_bounds__(192)
void attw_k(AWJobs js) {
    AWJob jb = js.j[blockIdx.x];
    const int t = threadIdx.x;
    const int k = t / 3, h = t - 3 * (t / 3);
    if (k < jb.din) {
        const float* wrow = jb.W + (size_t)k * HD + h * 32;
        const float* av = jb.a + h * 32;
        float s = 0.f;
        #pragma unroll
        for (int d = 0; d < 32; ++d) s = fmaf(wrow[d], av[d], s);
        jb.out[k * 3 + h] = s;
    }
}

// ---------------- CSR build ----------------
__global__ void zero_k(int* p, int n) {
    const int i = blockIdx.x * 256 + threadIdx.x;
    if (i < n) p[i] = 0;
}

__global__ void hist_k(const int* __restrict__ gd, const int* __restrict__ bd, int* __restrict__ cnt) {
    const int i = blockIdx.x * 256 + threadIdx.x;
    if (i < Ec) atomicAdd(&cnt[gd[i]], 1);
    else if (i < 2 * Ec) atomicAdd(&cnt[NN + bd[i - Ec]], 1);
}

__global__ __launch_bounds__(256)
void scan_a_k(const int* __restrict__ cnt, int* __restrict__ bsum) {
    const int rel = blockIdx.y, blk = blockIdx.x;
    const int i = blk * 256 + threadIdx.x;
    int v = (i < NN) ? cnt[rel * NN + i] : 0;
    #pragma unroll
    for (int d = 32; d; d >>= 1) v += __shfl_xor(v, d);
    __shared__ int ws[4];
    const int lane = threadIdx.x & 63, wid = threadIdx.x >> 6;
    if (lane == 0) ws[wid] = v;
    __syncthreads();
    if (threadIdx.x == 0) bsum[rel * SCB + blk] = ws[0] + ws[1] + ws[2] + ws[3];
}

__global__ __launch_bounds__(512)
void scan_b_k(int* __restrict__ bsum, int* __restrict__ off) {
    const int rel = blockIdx.x;
    __shared__ int ps[512];
    const int t = threadIdx.x;
    const int v = (t < SCB) ? bsum[rel * SCB + t] : 0;
    ps[t] = v;
    __syncthreads();
    for (int d = 1; d < 512; d <<= 1) {
        const int u = (t >= d) ? ps[t - d] : 0;
        __syncthreads();
        ps[t] += u;
        __syncthreads();
    }
    if (t < SCB) bsum[rel * SCB + t] = ps[t] - v;
    if (t == SCB - 1) off[rel * (NN + 1) + NN] = ps[t];
}

__global__ __launch_bounds__(256)
void scan_c_k(int* __restrict__ cnt, const int* __restrict__ bsum, int* __restrict__ off) {
    const int rel = blockIdx.y, blk = blockIdx.x;
    const int t = threadIdx.x;
    const int i = blk * 256 + t;
    const int v = (i < NN) ? cnt[rel * NN + i] : 0;
    const int lane = t & 63, wid = t >> 6;
    int incl = v;
    #pragma unroll
    for (int d = 1; d < 64; d <<= 1) {
        const int u = __shfl_up(incl, d);
        if (lane >= d) incl += u;
    }
    __shared__ int wsum[4];
    if (lane == 63) wsum[wid] = incl;
    __syncthreads();
    int base = 0;
    #pragma unroll
    for (int w = 0; w < 4; ++w) base += (w < wid) ? wsum[w] : 0;
    if (i < NN) {
        off[rel * (NN + 1) + i] = bsum[rel * SCB + blk] + base + incl - v;
        cnt[rel * NN + i] = 0;
    }
}

__global__ void fill_k(const int* __restrict__ gs, const int* __restrict__ gd,
                       const int* __restrict__ bs, const int* __restrict__ bd,
                       const int* __restrict__ off, int* __restrict__ cur, int* __restrict__ csr) {
    const int i = blockIdx.x * 256 + threadIdx.x;
    if (i < Ec) {
        const int d = gd[i];
        const int p = off[d] + atomicAdd(&cur[d], 1);
        csr[p] = gs[i];
    } else if (i < 2 * Ec) {
        const int d = bd[i - Ec];
        const int p = off[(NN + 1) + d] + atomicAdd(&cur[NN + d], 1);
        csr[Ec + p] = bs[i - Ec];
    }
}

// ---------------- dense transform: node-per-thread, W via uniform scalar loads ----------------
// jA (blockIdx.y==0): outF = fp16-packed messages. jB: outF = fp32 acc (res@W + bias).
template<int DIN>
__global__ __launch_bounds__(256)
void transform_k(TJob jA, TJob jB, int N) {
    const bool isA = (blockIdx.y == 0);
    const TJob j = isA ? jA : jB;
    const int n = blockIdx.x * 256 + threadIdx.x;
    if (n >= N) return;
    const float* __restrict__ Wg  = j.W;
    const float* __restrict__ Wsm = j.Wsm;
    const float* __restrict__ bs  = j.bias;

    float acc[HD];
    if (bs) {
        #pragma unroll
        for (int jo = 0; jo < HD; ++jo) acc[jo] = bs[jo];
    } else {
        #pragma unroll
        for (int jo = 0; jo < HD; ++jo) acc[jo] = 0.f;
    }
    float e0 = 0.f, e1 = 0.f, e2 = 0.f;

    const float4* __restrict__ xrow = reinterpret_cast<const float4*>(j.X + (size_t)n * DIN);
    #pragma unroll 1
    for (int kk = 0; kk < DIN / 4; ++kk) {
        const float4 xv = xrow[kk];
        float xs[4] = { xv.x, xv.y, xv.z, xv.w };
        #pragma unroll
        for (int q = 0; q < 4; ++q) {
            const int k = kk * 4 + q;
            const float x = xs[q];
            e0 = fmaf(x, Wsm[k * 3 + 0], e0);
            e1 = fmaf(x, Wsm[k * 3 + 1], e1);
            e2 = fmaf(x, Wsm[k * 3 + 2], e2);
            #pragma unroll
            for (int jo = 0; jo < HD; ++jo)
                acc[jo] = fmaf(x, Wg[k * HD + jo], acc[jo]);
        }
    }
    j.outE[(size_t)n * 3 + 0] = e0;
    j.outE[(size_t)n * 3 + 1] = e1;
    j.outE[(size_t)n * 3 + 2] = e2;
    if (isA) {
        // pack 96 channels -> 48 half2, 16B stores
        unsigned int* __restrict__ op = (unsigned int*)jA.outF + (size_t)n * 48;
        #pragma unroll
        for (int jo = 0; jo < HD; jo += 8) {
            uint4 u;
            u.x = __builtin_bit_cast(unsigned int, __float22half2_rn(make_float2(acc[jo    ], acc[jo + 1])));
            u.y = __builtin_bit_cast(unsigned int, __float22half2_rn(make_float2(acc[jo + 2], acc[jo + 3])));
            u.z = __builtin_bit_cast(unsigned int, __float22half2_rn(make_float2(acc[jo + 4], acc[jo + 5])));
            u.w = __builtin_bit_cast(unsigned int, __float22half2_rn(make_float2(acc[jo + 6], acc[jo + 7])));
            *reinterpret_cast<uint4*>(op + jo / 2) = u;
        }
    } else {
        float* __restrict__ op = (float*)jB.outF + (size_t)n * HD;
        #pragma unroll
        for (int jo = 0; jo < HD; jo += 4) {
            float4 o; o.x = acc[jo]; o.y = acc[jo + 1]; o.z = acc[jo + 2]; o.w = acc[jo + 3];
            *reinterpret_cast<float4*>(op + jo) = o;
        }
    }
}

// ---------------- fused softmax + aggregation + linear + BN + ReLU ----------------
// Block = 256 threads = 4 waves = 4 dst nodes. Phase1: per-wave GAT aggregate (fp16 fs
// gather, channel-pairs on lanes 0..47) + residual -> xLDS. Phase2: 128 threads do
// (4 nodes x 32 out) linear + BN + ReLU -> final output.
__global__ __launch_bounds__(256)
void agg_lin_k(const int* __restrict__ off, const int* __restrict__ srcs,
               const float* __restrict__ el, const float* __restrict__ er,
               const __half2* __restrict__ fsh, const float* __restrict__ accres,
               const float* __restrict__ Wl, const float* __restrict__ bl,
               const float* __restrict__ bn, float* __restrict__ out, int N)
{
    __shared__ float4 wLDS[4][64];   // per edge: {w0, w1, w2, src-as-float}
    __shared__ float  xLDS[4][100];  // aggregated 96-vector per node (+pad)

    const int wid  = threadIdx.x >> 6;
    const int lane = threadIdx.x & 63;
    const int node = blockIdx.x * 4 + wid;

    if (node < N) {
        const int o0 = off[node], o1 = off[node + 1];
        const int deg = o1 - o0;
        const float er0 = er[node * 3 + 0], er1 = er[node * 3 + 1], er2 = er[node * 3 + 2];
        const int h2 = lane >> 4;          // head for channel pair (2*lane, 2*lane+1), lane<48
        float a0 = 0.f, a1 = 0.f;

        if (deg <= 64) {
            // ---- fast path: 1 edge per lane ----
            const int p = o0 + lane;
            const bool has = p < o1;
            const int s = has ? srcs[p] : 0;
            float v0 = -INFINITY, v1 = -INFINITY, v2 = -INFINITY;
            if (has) {
                v0 = el[s * 3 + 0] + er0; v0 = v0 > 0.f ? v0 : SLOPE * v0;
                v1 = el[s * 3 + 1] + er1; v1 = v1 > 0.f ? v1 : SLOPE * v1;
                v2 = el[s * 3 + 2] + er2; v2 = v2 > 0.f ? v2 : SLOPE * v2;
            }
            float m0 = v0, m1 = v1, m2 = v2;
            #pragma unroll
            for (int d = 32; d; d >>= 1) {
                m0 = fmaxf(m0, __shfl_xor(m0, d));
                m1 = fmaxf(m1, __shfl_xor(m1, d));
                m2 = fmaxf(m2, __shfl_xor(m2, d));
            }
            const float e0x = has ? __expf(v0 - m0) : 0.f;
            const float e1x = has ? __expf(v1 - m1) : 0.f;
            const float e2x = has ? __expf(v2 - m2) : 0.f;
            float s0 = e0x, s1 = e1x, s2 = e2x;
            #pragma unroll
            for (int d = 32; d; d >>= 1) {
                s0 += __shfl_xor(s0, d); s1 += __shfl_xor(s1, d); s2 += __shfl_xor(s2, d);
            }
            float4 wv;
            wv.x = e0x * (s0 > 0.f ? 1.f / s0 : 0.f);
            wv.y = e1x * (s1 > 0.f ? 1.f / s1 : 0.f);
            wv.z = e2x * (s2 > 0.f ? 1.f / s2 : 0.f);
            wv.w = __int_as_float(s);
            wLDS[wid][lane] = wv;        // same-wave write-then-read; compiler orders lgkmcnt
            if (lane < 48) {
                #pragma unroll 2
                for (int jj = 0; jj < deg; ++jj) {
                    const float4 w4 = wLDS[wid][jj];            // broadcast read
                    const int sj = __float_as_int(w4.w);
                    const float wgt = (h2 == 0) ? w4.x : (h2 == 1) ? w4.y : w4.z;
                    const float2 f = __half22float2(fsh[(size_t)sj * 48 + lane]);
                    a0 = fmaf(f.x, wgt, a0);
                    a1 = fmaf(f.y, wgt, a1);
                }
            }
        } else {
            // ---- generic path (deg > 64), rare ----
            float m0 = -INFINITY, m1 = -INFINITY, m2 = -INFINITY;
            for (int p = o0 + lane; p < o1; p += 64) {
                const int s = srcs[p];
                float v0 = el[s * 3 + 0] + er0; v0 = v0 > 0.f ? v0 : SLOPE * v0;
                float v1 = el[s * 3 + 1] + er1; v1 = v1 > 0.f ? v1 : SLOPE * v1;
                float v2 = el[s * 3 + 2] + er2; v2 = v2 > 0.f ? v2 : SLOPE * v2;
                m0 = fmaxf(m0, v0); m1 = fmaxf(m1, v1); m2 = fmaxf(m2, v2);
            }
            #pragma unroll
            for (int d = 32; d; d >>= 1) {
                m0 = fmaxf(m0, __shfl_xor(m0, d));
                m1 = fmaxf(m1, __shfl_xor(m1, d));
                m2 = fmaxf(m2, __shfl_xor(m2, d));
            }
            float s0 = 0.f, s1 = 0.f, s2 = 0.f;
            for (int p = o0 + lane; p < o1; p += 64) {
                const int s = srcs[p];
                float v0 = el[s * 3 + 0] + er0; v0 = v0 > 0.f ? v0 : SLOPE * v0;
                float v1 = el[s * 3 + 1] + er1; v1 = v1 > 0.f ? v1 : SLOPE * v1;
                float v2 = el[s * 3 + 2] + er2; v2 = v2 > 0.f ? v2 : SLOPE * v2;
                s0 += __expf(v0 - m0); s1 += __expf(v1 - m1); s2 += __expf(v2 - m2);
            }
            #pragma unroll
            for (int d = 32; d; d >>= 1) {
                s0 += __shfl_xor(s0, d); s1 += __shfl_xor(s1, d); s2 += __shfl_xor(s2, d);
            }
            const float r0 = s0 > 0.f ? 1.f / s0 : 0.f;
            const float r1 = s1 > 0.f ? 1.f / s1 : 0.f;
            const float r2 = s2 > 0.f ? 1.f / s2 : 0.f;
            if (lane < 48) {
                const float erh = (h2 == 0) ? er0 : (h2 == 1) ? er1 : er2;
                const float mh  = (h2 == 0) ? m0  : (h2 == 1) ? m1  : m2;
                const float rh  = (h2 == 0) ? r0  : (h2 == 1) ? r1  : r2;
                for (int p = o0; p < o1; ++p) {
                    const int s = srcs[p];
                    float v = el[s * 3 + h2] + erh; v = v > 0.f ? v : SLOPE * v;
                    const float wgt = __expf(v - mh) * rh;
                    const float2 f = __half22float2(fsh[(size_t)s * 48 + lane]);
                    a0 = fmaf(f.x, wgt, a0);
                    a1 = fmaf(f.y, wgt, a1);
                }
            }
        }
        if (lane < 48) {
            const float2 rv = *reinterpret_cast<const float2*>(&accres[(size_t)node * HD + 2 * lane]);
            float2 xv; xv.x = a0 + rv.x; xv.y = a1 + rv.y;
            *reinterpret_cast<float2*>(&xLDS[wid][2 * lane]) = xv;
        }
    }
    __syncthreads();

    // ---- phase 2: linear(96->32) + BN + ReLU, 128 threads = 4 nodes x 32 outputs ----
    const int t = threadIdx.x;
    if (t < 128) {
        const int nd = t >> 5, o = t & 31;
        const int node2 = blockIdx.x * 4 + nd;
        if (node2 < N) {
            float y = bl[o];
            const float* xr = xLDS[nd];
            #pragma unroll 4
            for (int k = 0; k < HD; ++k)
                y = fmaf(xr[k], Wl[k * DOUT + o], y);
            const float gamma = bn[o], beta = bn[DOUT + o], mean = bn[2 * DOUT + o], var = bn[3 * DOUT + o];
            const float r = (y - mean) * gamma * rsqrtf(var + BN_EPS) + beta;
            out[(size_t)node2 * DOUT + o] = fmaxf(r, 0.f);
        }
    }
}

// ---------------- host ----------------
extern "C" void kernel_launch(void* const* d_in, const int* in_sizes, int n_in,
                              void* d_out, int out_size, void* d_ws, size_t ws_size,
                              hipStream_t stream)
{
    const float* emb_user = (const float*)d_in[0];
    const float* emb_item = (const float*)d_in[1];
    const float* W1    = (const float*)d_in[2];
    const float* attn1 = (const float*)d_in[3];
    const float* res1  = (const float*)d_in[4];
    const float* bias1 = (const float*)d_in[5];
    const float* nnW1  = (const float*)d_in[6];
    const float* nnb1  = (const float*)d_in[7];
    const float* bn1   = (const float*)d_in[8];
    const float* W2    = (const float*)d_in[9];
    const float* attn2 = (const float*)d_in[10];
    const float* res2  = (const float*)d_in[11];
    const float* bias2 = (const float*)d_in[12];
    const float* nnW2  = (const float*)d_in[13];
    const float* nnb2  = (const float*)d_in[14];
    const float* bn2   = (const float*)d_in[15];
    const int* go_src   = (const int*)d_in[16];
    const int* go_dst   = (const int*)d_in[17];
    const int* back_src = (const int*)d_in[18];
    const int* back_dst = (const int*)d_in[19];

    // workspace layout (~91 MB)
    int* icnt = (int*)d_ws;                    // 2*NN
    int* ioff = icnt + 2 * NN;                 // 2*(NN+1)
    int* icsr = ioff + 2 * (NN + 1);           // 2*Ec
    int* ibs  = icsr + 2 * Ec;                 // 2*SCB
    float* aw = (float*)((int*)d_ws + 1400800);// 8*192 attn weights (+pad)
    float* fsraw = aw + 2048;                  // NN*96 halves = NN*48 float-slots
    __half2* fsh = (__half2*)fsraw;
    float* acc = fsraw + (size_t)NN * 48;      // NN*96 fp32 (residual base)
    float* el  = acc + (size_t)NN * HD;        // NN*3
    float* er  = el + (size_t)NN * 3;          // NN*3
    float* hu1 = er + (size_t)NN * 3;          // NN*32
    float* hi1 = hu1 + (size_t)NN * DOUT;      // NN*32

    float* out_user = (float*)d_out;
    float* out_item = out_user + (size_t)NN * DOUT;

    // 1) attention pre-reduction
    {
        const float* Wm[4] = { W1, W1 + 64 * HD, W2, W2 + 32 * HD };
        const float* Am[4] = { attn1, attn1 + 192, attn2, attn2 + 192 };
        const int dins[4] = { 64, 64, 32, 32 };
        AWJobs js;
        for (int r = 0; r < 4; ++r)
            for (int s = 0; s < 2; ++s)
                js.j[r * 2 + s] = { Wm[r], Am[r] + s * HD, aw + (size_t)(r * 2 + s) * 192, dins[r] };
        attw_k<<<8, 192, 0, stream>>>(js);
    }

    // 2) CSR build
    zero_k<<<(2 * NN + 255) / 256, 256, 0, stream>>>(icnt, 2 * NN);
    hist_k<<<(2 * Ec + 255) / 256, 256, 0, stream>>>(go_dst, back_dst, icnt);
    scan_a_k<<<dim3(SCB, 2), 256, 0, stream>>>(icnt, ibs);
    scan_b_k<<<2, 512, 0, stream>>>(ibs, ioff);
    scan_c_k<<<dim3(SCB, 2), 256, 0, stream>>>(icnt, ibs, ioff);
    fill_k<<<(2 * Ec + 255) / 256, 256, 0, stream>>>(go_src, go_dst, back_src, back_dst, ioff, icnt, icsr);

    auto run_rel = [&](int din, const float* srcX, const float* dstX,
                       const float* W, const float* resW, const float* bias,
                       const float* Wlft, const float* Wrgt,
                       const int* off, const int* csr,
                       const float* lW, const float* lb, const float* bnp, float* outp)
    {
        TJob jA = { srcX, W,    Wlft, nullptr, (void*)fsh, el };
        TJob jB = { dstX, resW, Wrgt, bias,    (void*)acc, er };
        dim3 g((NN + 255) / 256, 2);
        if (din == 64) transform_k<64><<<g, 256, 0, stream>>>(jA, jB, NN);
        else           transform_k<32><<<g, 256, 0, stream>>>(jA, jB, NN);
        agg_lin_k<<<(NN + 3) / 4, 256, 0, stream>>>(off, csr, el, er, fsh, acc, lW, lb, bnp, outp, NN);
    };

    // ---- layer 1 ----
    run_rel(64, emb_user, emb_item, W1,            res1,            bias1,
            aw + 0,    aw + 192,  ioff,          icsr,
            nnW1 + HD * DOUT, nnb1 + DOUT, bn1 + 4 * DOUT, hi1);          // 'go' -> items
    run_rel(64, emb_item, emb_user, W1 + 64 * HD,  res1 + 64 * HD,  bias1 + HD,
            aw + 384,  aw + 576,  ioff + NN + 1, icsr + Ec,
            nnW1, nnb1, bn1, hu1);                                         // 'back' -> users

    // ---- layer 2 ----
    run_rel(32, hu1, hi1, W2,           res2,           bias2,
            aw + 768,  aw + 960,  ioff,          icsr,
            nnW2 + HD * DOUT, nnb2 + DOUT, bn2 + 4 * DOUT, out_item);      // 'go' -> items
    run_rel(32, hi1, hu1, W2 + 32 * HD, res2 + 32 * HD, bias2 + HD,
            aw + 1152, aw + 1344, ioff + NN + 1, icsr + Ec,
            nnW2, nnb2, bn2, out_user);                                    // 'back' -> users

    (void)ibs;
}